// Round 16
// baseline (199.616 us; speedup 1.0000x reference)
//
#include <hip/hip_runtime.h>
#include <cmath>

typedef _Float16 f16;
typedef _Float16 f16x8 __attribute__((ext_vector_type(8)));
typedef float    f32x16 __attribute__((ext_vector_type(16)));

#define NK 1024
#define ND 64
#define NTOT 131072

// d_ws layout: [0,4KB) u32 counts[1024]; [4KB,8KB) f32 g[1024] = -0.5*||e_k||^2;
//              [8KB, 8KB+256KB) f16x8 fragbuf[16384]  (split E fragments, if ws fits)

// Fused prep: split E-fragments in MFMA frag order (bit-identical to the
// round-8 inline split) + counts zero + g. Tile T=t>>9 (32 codes each),
// ft=t&511, u=(ft>>6)&7, ln=ft&63; u4=u&3, islo=u>>2; code c=T*32+(ln&31);
// d0=u4*16+(ln>>5)*8.
__global__ __launch_bounds__(256) void vq_prep_all(const float* __restrict__ emb,
                                                   f16x8* __restrict__ frag,
                                                   unsigned int* __restrict__ counts,
                                                   float* __restrict__ g) {
    int t  = blockIdx.x * 256 + threadIdx.x;   // 0..16383
    int ft = t & 511;
    int T  = t >> 9;
    int u  = (ft >> 6) & 7;
    int ln = ft & 63;
    int u4 = u & 3, islo = u >> 2;
    int c  = (T << 5) + (ln & 31);
    int d0 = u4*16 + ((ln >> 5) << 3);
    const float4* src = reinterpret_cast<const float4*>(emb + ((size_t)c << 6) + d0);
    float4 va = src[0], vb = src[1];
    f16x8 o;
    if (islo) {
        o[0] = (f16)((va.x - (float)(f16)va.x) * 2048.0f);
        o[1] = (f16)((va.y - (float)(f16)va.y) * 2048.0f);
        o[2] = (f16)((va.z - (float)(f16)va.z) * 2048.0f);
        o[3] = (f16)((va.w - (float)(f16)va.w) * 2048.0f);
        o[4] = (f16)((vb.x - (float)(f16)vb.x) * 2048.0f);
        o[5] = (f16)((vb.y - (float)(f16)vb.y) * 2048.0f);
        o[6] = (f16)((vb.z - (float)(f16)vb.z) * 2048.0f);
        o[7] = (f16)((vb.w - (float)(f16)vb.w) * 2048.0f);
    } else {
        o[0] = (f16)va.x; o[1] = (f16)va.y; o[2] = (f16)va.z; o[3] = (f16)va.w;
        o[4] = (f16)vb.x; o[5] = (f16)vb.y; o[6] = (f16)vb.z; o[7] = (f16)vb.w;
    }
    frag[t] = o;

    if (t < NK) {
        counts[t] = 0u;
        const float4* row = reinterpret_cast<const float4*>(emb + (size_t)t * ND);
        float s = 0.0f;
#pragma unroll
        for (int i = 0; i < ND/4; ++i) {
            float4 v = row[i];
            s += v.x*v.x + v.y*v.y + v.z*v.z + v.w*v.w;
        }
        g[t] = -0.5f * s;
    }
}

// fp16 double-split MFMA distances — numerics bit-identical to round 8:
// dot = A0 + A1*2^-11 + A2*2^-22, m = dot + g in the epilogue.
// Geometry = round 14's measured-best: 512-thr blocks, 8 chunks of 128 codes,
// Ef[2][2048] dbuf via async global_load_lds, one barrier/chunk, setprio.
// Epilogue: tie-aware pairwise (m,code) max-TREE — identical selection
// semantics to the sequential scan (max, lowest code on ties; comparisons on
// bit-identical values) but dep-chain depth 4 instead of 16.
template<bool PRE>
__global__ __launch_bounds__(512, 2) void vq_main(const float* __restrict__ in,
                                                  const float* __restrict__ emb,
                                                  const float* __restrict__ g,
                                                  const f16x8* __restrict__ frag,
                                                  unsigned int* __restrict__ counts,
                                                  float* __restrict__ out_idx,
                                                  float* __restrict__ out_q) {
    __shared__ f16x8 Ef[2][2048];   // 64KB
    __shared__ float gs_all[1024];  // 4KB, loaded once

    const int tid  = threadIdx.x;
    const int lane = tid & 63;
    const int wv   = tid >> 6;
    const int col  = lane & 31;
    const int hi   = lane >> 5;

    const int task = blockIdx.x * 8 + wv;   // 4096 tasks, 32 queries each
    const int q0   = task << 5;
    const int b    = q0 >> 12;
    const int hw0  = q0 & 4095;
    const int q    = q0 + col;

    // ---- query B-frags: xh + xl'*2^-11 (xl' prescaled 2048) ----
    const float* xb = in + ((size_t)b << 18) + hw0 + col;
    f16x8 xh[4], xl[4];
#pragma unroll
    for (int s = 0; s < 4; ++s) {
#pragma unroll
        for (int j = 0; j < 8; ++j) {
            float xv = xb[(size_t)(s*16 + hi*8 + j) << 12];
            f16 h = (f16)xv;
            xh[s][j] = h;
            xl[s][j] = (f16)((xv - (float)h) * 2048.0f);
        }
    }

    float bestm = -3.4e38f;
    int   bestk = 0;
    const float c1 = 4.8828125e-4f;           // 2^-11
    const float c2 = 2.384185791015625e-7f;   // 2^-22

    // ---- async stage 128-code chunk cc into Ef[buf] (2048 frags, 32KB) ----
    auto STAGE = [&](int cc, int buf) {
        if constexpr (PRE) {
            const f16x8* fp = frag + cc*2048 + (wv << 6) + lane;  // per-lane src
#pragma unroll
            for (int i = 0; i < 4; ++i) {
                __builtin_amdgcn_global_load_lds(
                    (const __attribute__((address_space(1))) void*)(fp + i*512),
                    (__attribute__((address_space(3))) void*)&Ef[buf][i*512 + (wv << 6)],
                    16, 0, 0);
            }
        } else {
            // fallback: direct load+split+write (no cross-phase liveness)
#pragma unroll
            for (int i = 0; i < 4; ++i) {
                int f  = i*512 + tid;
                int tt = f >> 9;
                int u4 = (f >> 6) & 3;
                int ln = f & 63;
                int c  = (((cc << 2) + tt) << 5) + (ln & 31);
                int d0 = u4*16 + ((ln >> 5) << 3);
                const float4* src = reinterpret_cast<const float4*>(emb + ((size_t)c << 6) + d0);
                float4 va = src[0], vb = src[1];
                int islo = (f >> 8) & 1;
                f16x8 o;
                if (islo) {
                    o[0] = (f16)((va.x - (float)(f16)va.x) * 2048.0f);
                    o[1] = (f16)((va.y - (float)(f16)va.y) * 2048.0f);
                    o[2] = (f16)((va.z - (float)(f16)va.z) * 2048.0f);
                    o[3] = (f16)((va.w - (float)(f16)va.w) * 2048.0f);
                    o[4] = (f16)((vb.x - (float)(f16)vb.x) * 2048.0f);
                    o[5] = (f16)((vb.y - (float)(f16)vb.y) * 2048.0f);
                    o[6] = (f16)((vb.z - (float)(f16)vb.z) * 2048.0f);
                    o[7] = (f16)((vb.w - (float)(f16)vb.w) * 2048.0f);
                } else {
                    o[0] = (f16)va.x; o[1] = (f16)va.y; o[2] = (f16)va.z; o[3] = (f16)va.w;
                    o[4] = (f16)vb.x; o[5] = (f16)vb.y; o[6] = (f16)vb.z; o[7] = (f16)vb.w;
                }
                Ef[buf][f] = o;
            }
        }
    };

    // ---- g to LDS once ----
    gs_all[tid]       = g[tid];
    gs_all[tid + 512] = g[tid + 512];
    STAGE(0, 0);
    __syncthreads();   // drains vmcnt -> Ef[0] + gs_all ready

#pragma unroll 1
    for (int cc = 0; cc < 8; ++cc) {
        const int cur = cc & 1;
        if (cc < 7) STAGE(cc + 1, cur ^ 1);   // async under this chunk's MFMAs

#pragma unroll
        for (int tt = 0; tt < 4; ++tt) {
            const f16x8* fb = &Ef[cur][tt*512 + lane];
            f32x16 a0 = {}, a1 = {}, a2 = {};
            __builtin_amdgcn_s_setprio(1);
#pragma unroll
            for (int s = 0; s < 4; ++s) {
                f16x8 eh = fb[s*64];
                a0 = __builtin_amdgcn_mfma_f32_32x32x16_f16(eh, xh[s], a0, 0, 0, 0);
                a1 = __builtin_amdgcn_mfma_f32_32x32x16_f16(eh, xl[s], a1, 0, 0, 0);
                f16x8 el = fb[(4+s)*64];
                a1 = __builtin_amdgcn_mfma_f32_32x32x16_f16(el, xh[s], a1, 0, 0, 0);
                a2 = __builtin_amdgcn_mfma_f32_32x32x16_f16(el, xl[s], a2, 0, 0, 0);
            }
            __builtin_amdgcn_s_setprio(0);
            // ---- m = dot + g[code]; tie-aware pairwise max-tree ----
            const int kbase = (((cc << 2) + tt) << 5) + (hi << 2);
            const float* gp = &gs_all[(((cc << 2) + tt) << 5) + (hi << 2)];
            float4 g0 = *reinterpret_cast<const float4*>(gp);
            float4 g1 = *reinterpret_cast<const float4*>(gp + 8);
            float4 g2 = *reinterpret_cast<const float4*>(gp + 16);
            float4 g3 = *reinterpret_cast<const float4*>(gp + 24);
            float mv[16];
            int   ci[16];
#pragma unroll
            for (int r = 0; r < 16; ++r) {
                float m = fmaf(a2[r], c2, fmaf(a1[r], c1, a0[r]));
                float gg;
                switch (r >> 2) {
                    case 0: gg = (r&3)==0?g0.x:(r&3)==1?g0.y:(r&3)==2?g0.z:g0.w; break;
                    case 1: gg = (r&3)==0?g1.x:(r&3)==1?g1.y:(r&3)==2?g1.z:g1.w; break;
                    case 2: gg = (r&3)==0?g2.x:(r&3)==1?g2.y:(r&3)==2?g2.z:g2.w; break;
                    default:gg = (r&3)==0?g3.x:(r&3)==1?g3.y:(r&3)==2?g3.z:g3.w; break;
                }
                mv[r] = m + gg;                         // bit-identical to prior m
                ci[r] = kbase + (r & 3) + ((r >> 2) << 3);  // ascends with r
            }
            // tree: left operand always lower code -> '>=' keeps lowest code on ties
#pragma unroll
            for (int st = 1; st < 16; st <<= 1) {
#pragma unroll
                for (int r0 = 0; r0 < 16; r0 += (st << 1)) {
                    bool ge = mv[r0] >= mv[r0 + st];
                    mv[r0] = ge ? mv[r0] : mv[r0 + st];
                    ci[r0] = ge ? ci[r0] : ci[r0 + st];
                }
            }
            if (mv[0] > bestm) { bestm = mv[0]; bestk = ci[0]; }  // strict > = first tile wins
        }

        __syncthreads();   // drains vmcnt: next buffer complete; Ef[cur] free
    }

    // ---- merge half-wave candidates (lower code wins ties) ----
    {
        float ob = __shfl_xor(bestm, 32, 64);
        int   oi = __shfl_xor(bestk, 32, 64);
        if (ob > bestm || (ob == bestm && oi < bestk)) { bestm = ob; bestk = oi; }
    }

    // ---- indices (as float) + histogram ----
    if (hi == 0) {
        out_idx[q] = (float)bestk;
        atomicAdd(&counts[bestk], 1u);
    }

    // ---- quantized (B,C,H,W): gather emb row (L2-hot), coalesced stores ----
    const float* er = emb + ((size_t)bestk << 6);
    float* ob_ = out_q + ((size_t)b << 18) + hw0 + col;
#pragma unroll
    for (int c4 = 0; c4 < 32; ++c4) {
        int c = hi*32 + c4;
        ob_[(size_t)c << 12] = er[c];
    }
}

__global__ __launch_bounds__(1024) void vq_perp(const unsigned int* __restrict__ counts,
                                                float* __restrict__ out_p) {
    __shared__ float red[16];
    int tid = threadIdx.x;  // 1024
    float p = (float)counts[tid] * (1.0f / (float)NTOT);
    float t = p * logf(p + 1e-10f);
#pragma unroll
    for (int m = 1; m < 64; m <<= 1) t += __shfl_xor(t, m, 64);
    if ((tid & 63) == 0) red[tid >> 6] = t;
    __syncthreads();
    if (tid < 16) {
        float s = red[tid];
#pragma unroll
        for (int m = 1; m < 16; m <<= 1) s += __shfl_xor(s, m, 64);
        if (tid == 0) out_p[0] = expf(-s);
    }
}

extern "C" void kernel_launch(void* const* d_in, const int* in_sizes, int n_in,
                              void* d_out, int out_size, void* d_ws, size_t ws_size,
                              hipStream_t stream) {
    const float* in  = (const float*)d_in[0];   // (32, 64, 64, 64)
    const float* emb = (const float*)d_in[1];   // (1024, 64)
    float* out = (float*)d_out;

    unsigned int* counts = (unsigned int*)d_ws;
    float* g = (float*)d_ws + NK;
    f16x8* frag = (f16x8*)((char*)d_ws + 8192);

    float* out_idx = out;                       // 131072
    float* out_q   = out + NTOT;                // 8388608
    float* out_p   = out + NTOT + (size_t)NTOT * ND;  // 1

    const bool pre = ws_size >= (size_t)(8192 + 16384 * 16);

    vq_prep_all<<<64, 256, 0, stream>>>(emb, frag, counts, g);
    if (pre) {
        vq_main<true><<<512, 512, 0, stream>>>(in, emb, g, frag, counts, out_idx, out_q);
    } else {
        vq_main<false><<<512, 512, 0, stream>>>(in, emb, g, frag, counts, out_idx, out_q);
    }
    vq_perp<<<1, 1024, 0, stream>>>(counts, out_p);
}

// Round 17
// 122.015 us; speedup vs baseline: 1.6360x; 1.6360x over previous
//
#include <hip/hip_runtime.h>
#include <cmath>

typedef _Float16 f16;
typedef _Float16 f16x8 __attribute__((ext_vector_type(8)));
typedef float    f32x16 __attribute__((ext_vector_type(16)));

#define NK 1024
#define ND 64
#define NTOT 131072

// d_ws layout: [0,4KB) u32 counts[1024]; [4KB,8KB) f32 g[1024] = -0.5*||e_k||^2;
//              [8KB, 8KB+256KB) f16x8 fragbuf[16384]  (split E fragments, if ws fits)

// Fused prep: split E-fragments in MFMA frag order (bit-identical to the
// round-8 inline split) + counts zero + g. frag t: cc=t>>11, f=t&2047,
// tt=f>>9, u=(f>>6)&7, ln=f&63; u4=u&3, islo=u>>2; code c=((cc*4+tt)*32)+(ln&31);
// d0=u4*16+(ln>>5)*8.
__global__ __launch_bounds__(256) void vq_prep_all(const float* __restrict__ emb,
                                                   f16x8* __restrict__ frag,
                                                   unsigned int* __restrict__ counts,
                                                   float* __restrict__ g) {
    int t  = blockIdx.x * 256 + threadIdx.x;   // 0..16383
    int f  = t & 2047;
    int cc = t >> 11;
    int tt = f >> 9;
    int u  = (f >> 6) & 7;
    int ln = f & 63;
    int u4 = u & 3, islo = u >> 2;
    int c  = (((cc << 2) + tt) << 5) + (ln & 31);
    int d0 = u4*16 + ((ln >> 5) << 3);
    const float4* src = reinterpret_cast<const float4*>(emb + ((size_t)c << 6) + d0);
    float4 va = src[0], vb = src[1];
    f16x8 o;
    if (islo) {
        o[0] = (f16)((va.x - (float)(f16)va.x) * 2048.0f);
        o[1] = (f16)((va.y - (float)(f16)va.y) * 2048.0f);
        o[2] = (f16)((va.z - (float)(f16)va.z) * 2048.0f);
        o[3] = (f16)((va.w - (float)(f16)va.w) * 2048.0f);
        o[4] = (f16)((vb.x - (float)(f16)vb.x) * 2048.0f);
        o[5] = (f16)((vb.y - (float)(f16)vb.y) * 2048.0f);
        o[6] = (f16)((vb.z - (float)(f16)vb.z) * 2048.0f);
        o[7] = (f16)((vb.w - (float)(f16)vb.w) * 2048.0f);
    } else {
        o[0] = (f16)va.x; o[1] = (f16)va.y; o[2] = (f16)va.z; o[3] = (f16)va.w;
        o[4] = (f16)vb.x; o[5] = (f16)vb.y; o[6] = (f16)vb.z; o[7] = (f16)vb.w;
    }
    frag[t] = o;

    if (t < NK) {
        counts[t] = 0u;
        const float4* row = reinterpret_cast<const float4*>(emb + (size_t)t * ND);
        float s = 0.0f;
#pragma unroll
        for (int i = 0; i < ND/4; ++i) {
            float4 v = row[i];
            s += v.x*v.x + v.y*v.y + v.z*v.z + v.w*v.w;
        }
        g[t] = -0.5f * s;
    }
}

// fp16 double-split MFMA distances — numerics bit-identical to round 8:
// dot = A0 + A1*2^-11 + A2*2^-22, m = dot + g in the epilogue.
// Round-14 measured-best structure (111.4 us): 512-thr blocks, 8 chunks of
// 128 codes, Ef[2][2048] dbuf via async global_load_lds, one barrier/chunk,
// setprio around MFMAs. Epilogue: TWO independent 8-deep compare chains
// (same op count as the scalar scan r14 used — no register arrays, which
// round 16 showed double VALU issue — but half the dependency depth).
template<bool PRE>
__global__ __launch_bounds__(512, 2) void vq_main(const float* __restrict__ in,
                                                  const float* __restrict__ emb,
                                                  const float* __restrict__ g,
                                                  const f16x8* __restrict__ frag,
                                                  unsigned int* __restrict__ counts,
                                                  float* __restrict__ out_idx,
                                                  float* __restrict__ out_q) {
    __shared__ f16x8 Ef[2][2048];   // 64KB
    __shared__ float gs_all[1024];  // 4KB, loaded once

    const int tid  = threadIdx.x;
    const int lane = tid & 63;
    const int wv   = tid >> 6;
    const int col  = lane & 31;
    const int hi   = lane >> 5;

    const int task = blockIdx.x * 8 + wv;   // 4096 tasks, 32 queries each
    const int q0   = task << 5;
    const int b    = q0 >> 12;
    const int hw0  = q0 & 4095;
    const int q    = q0 + col;

    // ---- query B-frags: xh + xl'*2^-11 (xl' prescaled 2048) ----
    const float* xb = in + ((size_t)b << 18) + hw0 + col;
    f16x8 xh[4], xl[4];
#pragma unroll
    for (int s = 0; s < 4; ++s) {
#pragma unroll
        for (int j = 0; j < 8; ++j) {
            float xv = xb[(size_t)(s*16 + hi*8 + j) << 12];
            f16 h = (f16)xv;
            xh[s][j] = h;
            xl[s][j] = (f16)((xv - (float)h) * 2048.0f);
        }
    }

    // two independent argmax chains (A: r=0..7, B: r=8..15)
    float bmA = -3.4e38f, bmB = -3.4e38f;
    int   bkA = 0,        bkB = 0;
    const float c1 = 4.8828125e-4f;           // 2^-11
    const float c2 = 2.384185791015625e-7f;   // 2^-22

    // ---- async stage chunk cc into Ef[buf]: HW DMA, no VGPR round-trip ----
    auto STAGE = [&](int cc, int buf) {
        if constexpr (PRE) {
            const f16x8* fp = frag + cc*2048 + (wv << 6) + lane;  // per-lane src
#pragma unroll
            for (int i = 0; i < 4; ++i) {
                __builtin_amdgcn_global_load_lds(
                    (const __attribute__((address_space(1))) void*)(fp + i*512),
                    (__attribute__((address_space(3))) void*)&Ef[buf][i*512 + (wv << 6)],
                    16, 0, 0);
            }
        } else {
            // fallback: direct load+split+write (no cross-phase liveness)
#pragma unroll
            for (int i = 0; i < 4; ++i) {
                int f  = i*512 + tid;
                int tt = f >> 9;
                int u4 = (f >> 6) & 3;
                int ln = f & 63;
                int c  = (((cc << 2) + tt) << 5) + (ln & 31);
                int d0 = u4*16 + ((ln >> 5) << 3);
                const float4* src = reinterpret_cast<const float4*>(emb + ((size_t)c << 6) + d0);
                float4 va = src[0], vb = src[1];
                int islo = (f >> 8) & 1;
                f16x8 o;
                if (islo) {
                    o[0] = (f16)((va.x - (float)(f16)va.x) * 2048.0f);
                    o[1] = (f16)((va.y - (float)(f16)va.y) * 2048.0f);
                    o[2] = (f16)((va.z - (float)(f16)va.z) * 2048.0f);
                    o[3] = (f16)((va.w - (float)(f16)va.w) * 2048.0f);
                    o[4] = (f16)((vb.x - (float)(f16)vb.x) * 2048.0f);
                    o[5] = (f16)((vb.y - (float)(f16)vb.y) * 2048.0f);
                    o[6] = (f16)((vb.z - (float)(f16)vb.z) * 2048.0f);
                    o[7] = (f16)((vb.w - (float)(f16)vb.w) * 2048.0f);
                } else {
                    o[0] = (f16)va.x; o[1] = (f16)va.y; o[2] = (f16)va.z; o[3] = (f16)va.w;
                    o[4] = (f16)vb.x; o[5] = (f16)vb.y; o[6] = (f16)vb.z; o[7] = (f16)vb.w;
                }
                Ef[buf][f] = o;
            }
        }
    };

    // ---- g to LDS once ----
    gs_all[tid]       = g[tid];
    gs_all[tid + 512] = g[tid + 512];
    STAGE(0, 0);
    __syncthreads();   // drains vmcnt -> Ef[0] + gs_all ready

#pragma unroll 1
    for (int cc = 0; cc < 8; ++cc) {
        const int cur = cc & 1;
        if (cc < 7) STAGE(cc + 1, cur ^ 1);   // async under this chunk's MFMAs

#pragma unroll
        for (int tt = 0; tt < 4; ++tt) {
            const f16x8* fb = &Ef[cur][tt*512 + lane];
            f32x16 a0 = {}, a1 = {}, a2 = {};
            __builtin_amdgcn_s_setprio(1);
#pragma unroll
            for (int s = 0; s < 4; ++s) {
                f16x8 eh = fb[s*64];
                a0 = __builtin_amdgcn_mfma_f32_32x32x16_f16(eh, xh[s], a0, 0, 0, 0);
                a1 = __builtin_amdgcn_mfma_f32_32x32x16_f16(eh, xl[s], a1, 0, 0, 0);
                f16x8 el = fb[(4+s)*64];
                a1 = __builtin_amdgcn_mfma_f32_32x32x16_f16(el, xh[s], a1, 0, 0, 0);
                a2 = __builtin_amdgcn_mfma_f32_32x32x16_f16(el, xl[s], a2, 0, 0, 0);
            }
            __builtin_amdgcn_s_setprio(0);
            // ---- m = dot + g[code]; maximize (== argmin dist) ----
            const int kb = (((cc << 2) + tt) << 5) + (hi << 2);
            const float* gp = &gs_all[kb];
            float4 g0 = *reinterpret_cast<const float4*>(gp);
            float4 g1 = *reinterpret_cast<const float4*>(gp + 8);
            float4 g2 = *reinterpret_cast<const float4*>(gp + 16);
            float4 g3 = *reinterpret_cast<const float4*>(gp + 24);
            // chain A: r=0..7 (codes kb+0..3, kb+8..11, ascending)
#pragma unroll
            for (int r = 0; r < 8; ++r) {
                float m = fmaf(a2[r], c2, fmaf(a1[r], c1, a0[r]));
                float gg = (r < 4) ? ((r&3)==0?g0.x:(r&3)==1?g0.y:(r&3)==2?g0.z:g0.w)
                                   : ((r&3)==0?g1.x:(r&3)==1?g1.y:(r&3)==2?g1.z:g1.w);
                m += gg;
                int code = kb + (r & 3) + ((r >> 2) << 3);
                if (m > bmA) { bmA = m; bkA = code; }   // strict > = first-min
            }
            // chain B: r=8..15 (codes kb+16..19, kb+24..27, ascending)
#pragma unroll
            for (int r = 8; r < 16; ++r) {
                float m = fmaf(a2[r], c2, fmaf(a1[r], c1, a0[r]));
                float gg = (r < 12) ? ((r&3)==0?g2.x:(r&3)==1?g2.y:(r&3)==2?g2.z:g2.w)
                                    : ((r&3)==0?g3.x:(r&3)==1?g3.y:(r&3)==2?g3.z:g3.w);
                m += gg;
                int code = kb + (r & 3) + ((r >> 2) << 3);
                if (m > bmB) { bmB = m; bkB = code; }
            }
        }

        __syncthreads();   // drains vmcnt: next buffer complete; Ef[cur] free
    }

    // ---- merge chains (lower code wins ties), then half-wave merge ----
    float bestm = bmA;
    int   bestk = bkA;
    if (bmB > bestm || (bmB == bestm && bkB < bestk)) { bestm = bmB; bestk = bkB; }
    {
        float ob = __shfl_xor(bestm, 32, 64);
        int   oi = __shfl_xor(bestk, 32, 64);
        if (ob > bestm || (ob == bestm && oi < bestk)) { bestm = ob; bestk = oi; }
    }

    // ---- indices (as float) + histogram ----
    if (hi == 0) {
        out_idx[q] = (float)bestk;
        atomicAdd(&counts[bestk], 1u);
    }

    // ---- quantized (B,C,H,W): gather emb row (L2-hot), coalesced stores ----
    const float* er = emb + ((size_t)bestk << 6);
    float* ob_ = out_q + ((size_t)b << 18) + hw0 + col;
#pragma unroll
    for (int c4 = 0; c4 < 32; ++c4) {
        int c = hi*32 + c4;
        ob_[(size_t)c << 12] = er[c];
    }
}

__global__ __launch_bounds__(1024) void vq_perp(const unsigned int* __restrict__ counts,
                                                float* __restrict__ out_p) {
    __shared__ float red[16];
    int tid = threadIdx.x;  // 1024
    float p = (float)counts[tid] * (1.0f / (float)NTOT);
    float t = p * logf(p + 1e-10f);
#pragma unroll
    for (int m = 1; m < 64; m <<= 1) t += __shfl_xor(t, m, 64);
    if ((tid & 63) == 0) red[tid >> 6] = t;
    __syncthreads();
    if (tid < 16) {
        float s = red[tid];
#pragma unroll
        for (int m = 1; m < 16; m <<= 1) s += __shfl_xor(s, m, 64);
        if (tid == 0) out_p[0] = expf(-s);
    }
}

extern "C" void kernel_launch(void* const* d_in, const int* in_sizes, int n_in,
                              void* d_out, int out_size, void* d_ws, size_t ws_size,
                              hipStream_t stream) {
    const float* in  = (const float*)d_in[0];   // (32, 64, 64, 64)
    const float* emb = (const float*)d_in[1];   // (1024, 64)
    float* out = (float*)d_out;

    unsigned int* counts = (unsigned int*)d_ws;
    float* g = (float*)d_ws + NK;
    f16x8* frag = (f16x8*)((char*)d_ws + 8192);

    float* out_idx = out;                       // 131072
    float* out_q   = out + NTOT;                // 8388608
    float* out_p   = out + NTOT + (size_t)NTOT * ND;  // 1

    const bool pre = ws_size >= (size_t)(8192 + 16384 * 16);

    vq_prep_all<<<64, 256, 0, stream>>>(emb, frag, counts, g);
    if (pre) {
        vq_main<true><<<512, 512, 0, stream>>>(in, emb, g, frag, counts, out_idx, out_q);
    } else {
        vq_main<false><<<512, 512, 0, stream>>>(in, emb, g, frag, counts, out_idx, out_q);
    }
    vq_perp<<<1, 1024, 0, stream>>>(counts, out_p);
}

// Round 18
// 111.163 us; speedup vs baseline: 1.7957x; 1.0976x over previous
//
#include <hip/hip_runtime.h>
#include <cmath>

typedef _Float16 f16;
typedef _Float16 f16x8 __attribute__((ext_vector_type(8)));
typedef float    f32x16 __attribute__((ext_vector_type(16)));

#define NK 1024
#define ND 64
#define NTOT 131072

// d_ws layout: [0,4KB) u32 counts[1024]; [4KB,8KB) f32 g[1024] = -0.5*||e_k||^2;
//              [8KB, 8KB+256KB) f16x8 fragbuf[16384]  (split E fragments, if ws fits)

// Fused prep: split E-fragments in MFMA frag order (bit-identical to the
// round-8 inline split) + counts zero + g. frag t: cc=t>>11, f=t&2047,
// tt=f>>9, u=(f>>6)&7, ln=f&63; u4=u&3, islo=u>>2; code c=((cc*4+tt)*32)+(ln&31);
// d0=u4*16+(ln>>5)*8.
__global__ __launch_bounds__(256) void vq_prep_all(const float* __restrict__ emb,
                                                   f16x8* __restrict__ frag,
                                                   unsigned int* __restrict__ counts,
                                                   float* __restrict__ g) {
    int t  = blockIdx.x * 256 + threadIdx.x;   // 0..16383
    int f  = t & 2047;
    int cc = t >> 11;
    int tt = f >> 9;
    int u  = (f >> 6) & 7;
    int ln = f & 63;
    int u4 = u & 3, islo = u >> 2;
    int c  = (((cc << 2) + tt) << 5) + (ln & 31);
    int d0 = u4*16 + ((ln >> 5) << 3);
    const float4* src = reinterpret_cast<const float4*>(emb + ((size_t)c << 6) + d0);
    float4 va = src[0], vb = src[1];
    f16x8 o;
    if (islo) {
        o[0] = (f16)((va.x - (float)(f16)va.x) * 2048.0f);
        o[1] = (f16)((va.y - (float)(f16)va.y) * 2048.0f);
        o[2] = (f16)((va.z - (float)(f16)va.z) * 2048.0f);
        o[3] = (f16)((va.w - (float)(f16)va.w) * 2048.0f);
        o[4] = (f16)((vb.x - (float)(f16)vb.x) * 2048.0f);
        o[5] = (f16)((vb.y - (float)(f16)vb.y) * 2048.0f);
        o[6] = (f16)((vb.z - (float)(f16)vb.z) * 2048.0f);
        o[7] = (f16)((vb.w - (float)(f16)vb.w) * 2048.0f);
    } else {
        o[0] = (f16)va.x; o[1] = (f16)va.y; o[2] = (f16)va.z; o[3] = (f16)va.w;
        o[4] = (f16)vb.x; o[5] = (f16)vb.y; o[6] = (f16)vb.z; o[7] = (f16)vb.w;
    }
    frag[t] = o;

    if (t < NK) {
        counts[t] = 0u;
        const float4* row = reinterpret_cast<const float4*>(emb + (size_t)t * ND);
        float s = 0.0f;
#pragma unroll
        for (int i = 0; i < ND/4; ++i) {
            float4 v = row[i];
            s += v.x*v.x + v.y*v.y + v.z*v.z + v.w*v.w;
        }
        g[t] = -0.5f * s;
    }
}

// fp16 double-split MFMA distances — numerics bit-identical to round 8:
// dot = A0 + A1*2^-11 + A2*2^-22, m = dot + g in the epilogue.
// EXACT round-14 structure (measured best of the session, 111.4 us wall):
// 512-thr blocks, 8 chunks of 128 codes, Ef[2][2048] dbuf via async
// global_load_lds, one barrier/chunk, setprio around MFMAs, sequential
// 16-candidate scan epilogue (codegen-friendliest of 3 measured variants:
// scan=100us, tree=+110%, two-chain=+24% via 88-VGPR occupancy drop).
template<bool PRE>
__global__ __launch_bounds__(512, 2) void vq_main(const float* __restrict__ in,
                                                  const float* __restrict__ emb,
                                                  const float* __restrict__ g,
                                                  const f16x8* __restrict__ frag,
                                                  unsigned int* __restrict__ counts,
                                                  float* __restrict__ out_idx,
                                                  float* __restrict__ out_q) {
    __shared__ f16x8 Ef[2][2048];   // 64KB
    __shared__ float gs_all[1024];  // 4KB, loaded once

    const int tid  = threadIdx.x;
    const int lane = tid & 63;
    const int wv   = tid >> 6;
    const int col  = lane & 31;
    const int hi   = lane >> 5;

    const int task = blockIdx.x * 8 + wv;   // 4096 tasks, 32 queries each
    const int q0   = task << 5;
    const int b    = q0 >> 12;
    const int hw0  = q0 & 4095;
    const int q    = q0 + col;

    // ---- query B-frags: xh + xl'*2^-11 (xl' prescaled 2048) ----
    const float* xb = in + ((size_t)b << 18) + hw0 + col;
    f16x8 xh[4], xl[4];
#pragma unroll
    for (int s = 0; s < 4; ++s) {
#pragma unroll
        for (int j = 0; j < 8; ++j) {
            float xv = xb[(size_t)(s*16 + hi*8 + j) << 12];
            f16 h = (f16)xv;
            xh[s][j] = h;
            xl[s][j] = (f16)((xv - (float)h) * 2048.0f);
        }
    }

    float bestm = -3.4e38f;
    int   bestk = 0;
    const float c1 = 4.8828125e-4f;           // 2^-11
    const float c2 = 2.384185791015625e-7f;   // 2^-22

    // ---- async stage chunk cc into Ef[buf]: HW DMA, no VGPR round-trip ----
    auto STAGE = [&](int cc, int buf) {
        if constexpr (PRE) {
            const f16x8* fp = frag + cc*2048 + (wv << 6) + lane;  // per-lane src
#pragma unroll
            for (int i = 0; i < 4; ++i) {
                __builtin_amdgcn_global_load_lds(
                    (const __attribute__((address_space(1))) void*)(fp + i*512),
                    (__attribute__((address_space(3))) void*)&Ef[buf][i*512 + (wv << 6)],
                    16, 0, 0);
            }
        } else {
            // fallback: direct load+split+write (no cross-phase liveness)
#pragma unroll
            for (int i = 0; i < 4; ++i) {
                int f  = i*512 + tid;
                int tt = f >> 9;
                int u4 = (f >> 6) & 3;
                int ln = f & 63;
                int c  = (((cc << 2) + tt) << 5) + (ln & 31);
                int d0 = u4*16 + ((ln >> 5) << 3);
                const float4* src = reinterpret_cast<const float4*>(emb + ((size_t)c << 6) + d0);
                float4 va = src[0], vb = src[1];
                int islo = (f >> 8) & 1;
                f16x8 o;
                if (islo) {
                    o[0] = (f16)((va.x - (float)(f16)va.x) * 2048.0f);
                    o[1] = (f16)((va.y - (float)(f16)va.y) * 2048.0f);
                    o[2] = (f16)((va.z - (float)(f16)va.z) * 2048.0f);
                    o[3] = (f16)((va.w - (float)(f16)va.w) * 2048.0f);
                    o[4] = (f16)((vb.x - (float)(f16)vb.x) * 2048.0f);
                    o[5] = (f16)((vb.y - (float)(f16)vb.y) * 2048.0f);
                    o[6] = (f16)((vb.z - (float)(f16)vb.z) * 2048.0f);
                    o[7] = (f16)((vb.w - (float)(f16)vb.w) * 2048.0f);
                } else {
                    o[0] = (f16)va.x; o[1] = (f16)va.y; o[2] = (f16)va.z; o[3] = (f16)va.w;
                    o[4] = (f16)vb.x; o[5] = (f16)vb.y; o[6] = (f16)vb.z; o[7] = (f16)vb.w;
                }
                Ef[buf][f] = o;
            }
        }
    };

    // ---- g to LDS once ----
    gs_all[tid]       = g[tid];
    gs_all[tid + 512] = g[tid + 512];
    STAGE(0, 0);
    __syncthreads();   // drains vmcnt -> Ef[0] + gs_all ready

#pragma unroll 1
    for (int cc = 0; cc < 8; ++cc) {
        const int cur = cc & 1;
        if (cc < 7) STAGE(cc + 1, cur ^ 1);   // async under this chunk's MFMAs

#pragma unroll
        for (int tt = 0; tt < 4; ++tt) {
            const f16x8* fb = &Ef[cur][tt*512 + lane];
            f32x16 a0 = {}, a1 = {}, a2 = {};
            __builtin_amdgcn_s_setprio(1);
#pragma unroll
            for (int s = 0; s < 4; ++s) {
                f16x8 eh = fb[s*64];
                a0 = __builtin_amdgcn_mfma_f32_32x32x16_f16(eh, xh[s], a0, 0, 0, 0);
                a1 = __builtin_amdgcn_mfma_f32_32x32x16_f16(eh, xl[s], a1, 0, 0, 0);
                f16x8 el = fb[(4+s)*64];
                a1 = __builtin_amdgcn_mfma_f32_32x32x16_f16(el, xh[s], a1, 0, 0, 0);
                a2 = __builtin_amdgcn_mfma_f32_32x32x16_f16(el, xl[s], a2, 0, 0, 0);
            }
            __builtin_amdgcn_s_setprio(0);
            // ---- m = dot + g[code]; maximize (== argmin dist) ----
            const int kbase = (((cc << 2) + tt) << 5);
            const float* gp = &gs_all[kbase + (hi << 2)];
            float4 g0 = *reinterpret_cast<const float4*>(gp);
            float4 g1 = *reinterpret_cast<const float4*>(gp + 8);
            float4 g2 = *reinterpret_cast<const float4*>(gp + 16);
            float4 g3 = *reinterpret_cast<const float4*>(gp + 24);
#pragma unroll
            for (int r = 0; r < 16; ++r) {
                float m = fmaf(a2[r], c2, fmaf(a1[r], c1, a0[r]));
                float gg;
                switch (r >> 2) {
                    case 0: gg = (r&3)==0?g0.x:(r&3)==1?g0.y:(r&3)==2?g0.z:g0.w; break;
                    case 1: gg = (r&3)==0?g1.x:(r&3)==1?g1.y:(r&3)==2?g1.z:g1.w; break;
                    case 2: gg = (r&3)==0?g2.x:(r&3)==1?g2.y:(r&3)==2?g2.z:g2.w; break;
                    default:gg = (r&3)==0?g3.x:(r&3)==1?g3.y:(r&3)==2?g3.z:g3.w; break;
                }
                m += gg;
                // code rows ascend with r within this lane -> strict > = first-min
                int code = kbase + (r & 3) + ((r >> 2) << 3) + (hi << 2);
                if (m > bestm) { bestm = m; bestk = code; }
            }
        }

        __syncthreads();   // drains vmcnt: next buffer complete; Ef[cur] free
    }

    // ---- merge half-wave candidates (lower code wins ties) ----
    {
        float ob = __shfl_xor(bestm, 32, 64);
        int   oi = __shfl_xor(bestk, 32, 64);
        if (ob > bestm || (ob == bestm && oi < bestk)) { bestm = ob; bestk = oi; }
    }

    // ---- indices (as float) + histogram ----
    if (hi == 0) {
        out_idx[q] = (float)bestk;
        atomicAdd(&counts[bestk], 1u);
    }

    // ---- quantized (B,C,H,W): gather emb row (L2-hot), coalesced stores ----
    const float* er = emb + ((size_t)bestk << 6);
    float* ob_ = out_q + ((size_t)b << 18) + hw0 + col;
#pragma unroll
    for (int c4 = 0; c4 < 32; ++c4) {
        int c = hi*32 + c4;
        ob_[(size_t)c << 12] = er[c];
    }
}

__global__ __launch_bounds__(1024) void vq_perp(const unsigned int* __restrict__ counts,
                                                float* __restrict__ out_p) {
    __shared__ float red[16];
    int tid = threadIdx.x;  // 1024
    float p = (float)counts[tid] * (1.0f / (float)NTOT);
    float t = p * logf(p + 1e-10f);
#pragma unroll
    for (int m = 1; m < 64; m <<= 1) t += __shfl_xor(t, m, 64);
    if ((tid & 63) == 0) red[tid >> 6] = t;
    __syncthreads();
    if (tid < 16) {
        float s = red[tid];
#pragma unroll
        for (int m = 1; m < 16; m <<= 1) s += __shfl_xor(s, m, 64);
        if (tid == 0) out_p[0] = expf(-s);
    }
}

extern "C" void kernel_launch(void* const* d_in, const int* in_sizes, int n_in,
                              void* d_out, int out_size, void* d_ws, size_t ws_size,
                              hipStream_t stream) {
    const float* in  = (const float*)d_in[0];   // (32, 64, 64, 64)
    const float* emb = (const float*)d_in[1];   // (1024, 64)
    float* out = (float*)d_out;

    unsigned int* counts = (unsigned int*)d_ws;
    float* g = (float*)d_ws + NK;
    f16x8* frag = (f16x8*)((char*)d_ws + 8192);

    float* out_idx = out;                       // 131072
    float* out_q   = out + NTOT;                // 8388608
    float* out_p   = out + NTOT + (size_t)NTOT * ND;  // 1

    const bool pre = ws_size >= (size_t)(8192 + 16384 * 16);

    vq_prep_all<<<64, 256, 0, stream>>>(emb, frag, counts, g);
    if (pre) {
        vq_main<true><<<512, 512, 0, stream>>>(in, emb, g, frag, counts, out_idx, out_q);
    } else {
        vq_main<false><<<512, 512, 0, stream>>>(in, emb, g, frag, counts, out_idx, out_q);
    }
    vq_perp<<<1, 1024, 0, stream>>>(counts, out_p);
}